// Round 14
// baseline (210.917 us; speedup 1.0000x reference)
//
#include <hip/hip_runtime.h>
#include <math.h>

#define BATCH 2
#define DIM 192
#define HIMG 192
#define WIMG 192
#define NPIX (HIMG*WIMG)      // 36864
#define NPIXT ((size_t)BATCH*NPIX) // 73728 total pixel rows
#define HEADS 6
#define HC 32
#define NTOK 256
#define WDq 12
#define NWIN_B 144
#define NWIN (BATCH*NWIN_B)   // 288
#define RPE_N 961
#define SLABSZ ((size_t)NWIN*HEADS*NTOK*HC)   // 14,155,776 elems per q/k/v slab
#define XSP_E ((size_t)NPIXT*DIM)             // 14,155,776 u16 per split array
#define WSP_E ((size_t)(3*DIM+DIM)*DIM)       // 147,456 u16 (fragment-ordered)
#define VLP 264                                // k_attn V-stage row stride (u16)

typedef float f32x4 __attribute__((ext_vector_type(4)));
typedef short s16x8 __attribute__((ext_vector_type(8)));
typedef unsigned short u16;

__device__ __forceinline__ u16 f2bf(float f) {
  union { float f; unsigned u; } cv; cv.f = f;
  unsigned u = cv.u + 0x7fffu + ((cv.u >> 16) & 1u);   // RNE
  return (u16)(u >> 16);
}
__device__ __forceinline__ float bf2f(u16 h) {
  union { unsigned u; float f; } cv; cv.u = ((unsigned)h) << 16;
  return cv.f;
}
__device__ __forceinline__ void split2(float f, u16& hi, u16& lo) {
  hi = f2bf(f);
  lo = f2bf(f - bf2f(hi));
}
// async global->LDS, 16B per lane. LDS dest is wave-uniform base + lane*16.
__device__ __forceinline__ void gll16(const void* g, void* l) {
  __builtin_amdgcn_global_load_lds(
      (const __attribute__((address_space(1))) void*)g,
      (__attribute__((address_space(3))) void*)l, 16, 0, 0);
}

// ---------------------------------------------------------------------------
// T0: transpose x [b][c][pix] fp32 -> xT bf16 [b*pix][c] (float4 reads).
// ---------------------------------------------------------------------------
__global__ __launch_bounds__(256)
void k_xsplit(const float* __restrict__ x, u16* __restrict__ xhi) {
  const size_t P0 = (size_t)blockIdx.x * 64;
  const int b = (int)(P0 / NPIX);
  const int p0 = (int)(P0 % NPIX);
  __shared__ float lds[DIM][65];
  const int tid = threadIdx.x;
  const float* xb = x + (size_t)b*DIM*NPIX + p0;
  #pragma unroll
  for (int i = 0; i < 12; ++i) {
    const int idx = i*256 + tid;          // 0..3071
    const int c = idx >> 4;               // 0..191
    const int p4 = (idx & 15) << 2;       // 0..60
    const float4 v4 = *reinterpret_cast<const float4*>(xb + (size_t)c*NPIX + p4);
    lds[c][p4+0] = v4.x;
    lds[c][p4+1] = v4.y;
    lds[c][p4+2] = v4.z;
    lds[c][p4+3] = v4.w;
  }
  __syncthreads();
  const int wave = tid >> 6, lane = tid & 63;
  if (lane < 48) {
    const int c0 = lane * 4;
    #pragma unroll
    for (int rr = 0; rr < 16; ++rr) {
      const int p = wave*16 + rr;
      ushort4 vh;
      vh.x = f2bf(lds[c0+0][p]);
      vh.y = f2bf(lds[c0+1][p]);
      vh.z = f2bf(lds[c0+2][p]);
      vh.w = f2bf(lds[c0+3][p]);
      *reinterpret_cast<ushort4*>(xhi + (P0 + p)*DIM + c0) = vh;
    }
  }
}

// ---------------------------------------------------------------------------
// T1: split w_qkv/w_out into hi/lo u16 in MFMA-FRAGMENT order:
//   frag[(ot*6 + ks)*512 + lane*8 + i]  <->  w[row=ot*16+(lane&15)]
//                                             [k=ks*32+(lane>>4)*8+i]
// One A-fragment load in the GEMMs = one fully-coalesced 1KB wave load
// (was a 16-line gather at 384B row stride). ot 0..35 = wqkv, 36..47 = wout.
// ---------------------------------------------------------------------------
__global__ __launch_bounds__(256)
void k_wsplit(const float* __restrict__ wqkv, const float* __restrict__ wout,
              u16* __restrict__ whi, u16* __restrict__ wlo) {
  const int gid = blockIdx.x*256 + threadIdx.x;      // 0..18431
  const int ot = gid / 384;
  const int rem = gid - ot*384;
  const int ks = rem >> 6;
  const int lane = rem & 63;
  const int u = lane & 15, g = lane >> 4;
  const int row = ot*16 + u;
  const float* src = (row < 3*DIM) ? (wqkv + (size_t)row*DIM + ks*32 + g*8)
                                   : (wout + (size_t)(row - 3*DIM)*DIM + ks*32 + g*8);
  const float4 a = *reinterpret_cast<const float4*>(src);
  const float4 b = *reinterpret_cast<const float4*>(src + 4);
  const float fv[8] = {a.x, a.y, a.z, a.w, b.x, b.y, b.z, b.w};
  s16x8 vh, vl;
  #pragma unroll
  for (int i = 0; i < 8; ++i) {
    u16 h, l;
    split2(fv[i], h, l);
    vh[i] = (short)h; vl[i] = (short)l;
  }
  *reinterpret_cast<s16x8*>(whi + (size_t)gid*8) = vh;
  *reinterpret_cast<s16x8*>(wlo + (size_t)gid*8) = vl;
}

// ---------------------------------------------------------------------------
// K1: qkv = w_qkv @ x + b_qkv, 2-term split MFMA.
// R14: ALL 3 slabs per block (grid 1152): x staged ONCE per tile (was 3x),
// 432 MFMA/wave amortize the fixed per-block overhead, A-loads coalesced
// via the fragment-ordered W. Single-stage skeleton kept (one vmcnt(0),
// one barrier); slab loop not unrolled to bound code size/registers.
// ---------------------------------------------------------------------------
__global__ __launch_bounds__(256, 3)
void k_qkv_mfma(const u16* __restrict__ xhi,
                const u16* __restrict__ whiF, const u16* __restrict__ wloF,
                const float* __restrict__ bqkv, u16* __restrict__ qkv) {
  const size_t P0 = (size_t)blockIdx.x * 64;
  const int tid = threadIdx.x;
  const int wave = tid >> 6, lane = tid & 63;
  const int u = lane & 15, g = lane >> 4;
  const int o_w = wave * 48;                 // 4 waves cover 192 o

  // [chunk][64 rows x 64 k-elems] bf16, 8KB per plane, 24KB total
  __shared__ u16 lb[3][4096];

  // stage the whole 64pix x 192k x-tile (XOR-swizzled source, linear dest)
  #pragma unroll
  for (int c = 0; c < 3; ++c)
    #pragma unroll
    for (int rep = 0; rep < 2; ++rep) {
      const int s = (rep*4 + wave)*64 + lane;
      const int row = s >> 3, chl = s & 7;
      gll16(xhi + (P0 + row)*DIM + c*64 + ((chl ^ (row & 7)) * 8),
            &lb[c][(size_t)((rep*4 + wave)*64) * 8]);
    }

  asm volatile("s_waitcnt vmcnt(0)" ::: "memory");   // stage done
  __builtin_amdgcn_s_barrier();                      // the only barrier

  #pragma unroll 1
  for (int slab = 0; slab < 3; ++slab) {
    f32x4 acc[3][4];
    #pragma unroll
    for (int of = 0; of < 3; ++of)
      #pragma unroll
      for (int hf = 0; hf < 4; ++hf) acc[of][hf] = (f32x4){0.f,0.f,0.f,0.f};

    const int otb = slab*12 + wave*3;        // row-tile base for this wave
    #pragma unroll
    for (int ks = 0; ks < 6; ++ks) {
      s16x8 ah[3], al[3], bh[4];
      #pragma unroll
      for (int of = 0; of < 3; ++of) {
        const size_t fo = (size_t)(((otb + of)*6 + ks) << 9) + (lane << 3);
        ah[of] = *reinterpret_cast<const s16x8*>(whiF + fo);
        al[of] = *reinterpret_cast<const s16x8*>(wloF + fo);
      }
      #pragma unroll
      for (int hf = 0; hf < 4; ++hf) {
        const int row = hf*16 + u;
        const int ch = ((ks & 1)*4 + g) ^ (row & 7);
        bh[hf] = *reinterpret_cast<const s16x8*>(&lb[ks >> 1][row*64 + ch*8]);
      }
      #pragma unroll
      for (int of = 0; of < 3; ++of)
        #pragma unroll
        for (int hf = 0; hf < 4; ++hf)
          acc[of][hf] = __builtin_amdgcn_mfma_f32_16x16x32_bf16(ah[of], bh[hf], acc[of][hf], 0, 0, 0);
      #pragma unroll
      for (int of = 0; of < 3; ++of)
        #pragma unroll
        for (int hf = 0; hf < 4; ++hf)
          acc[of][hf] = __builtin_amdgcn_mfma_f32_16x16x32_bf16(al[of], bh[hf], acc[of][hf], 0, 0, 0);
    }

    // epilogue for this slab: windowed scatter, bf16
    u16* base = qkv + (size_t)slab * SLABSZ;
    const float* bq = bqkv + slab*DIM;
    #pragma unroll
    for (int of = 0; of < 3; ++of) {
      const int ob = o_w + of*16 + g*4;
      const int hd = ob >> 5, cc = ob & 31;
      const float4 bias = *reinterpret_cast<const float4*>(bq + ob);
      #pragma unroll
      for (int hf = 0; hf < 4; ++hf) {
        const size_t pix = P0 + hf*16 + u;
        const int b = (int)(pix / NPIX);
        const int p = (int)(pix % NPIX);
        const int h = p / WIMG, w = p % WIMG;
        const int win = b*NWIN_B + (h >> 4)*WDq + (w >> 4);
        const int t = (h & 15)*16 + (w & 15);
        const float v0 = acc[of][hf][0] + bias.x;
        const float v1 = acc[of][hf][1] + bias.y;
        const float v2 = acc[of][hf][2] + bias.z;
        const float v3 = acc[of][hf][3] + bias.w;
        if (slab == 2) {
          u16* p2 = base + (((size_t)(win*HEADS + hd))*HC + cc)*NTOK + t;
          p2[0*NTOK] = f2bf(v0);
          p2[1*NTOK] = f2bf(v1);
          p2[2*NTOK] = f2bf(v2);
          p2[3*NTOK] = f2bf(v3);
        } else {
          ushort4 st;
          st.x = f2bf(v0); st.y = f2bf(v1); st.z = f2bf(v2); st.w = f2bf(v3);
          *reinterpret_cast<ushort4*>(base + (((size_t)(win*HEADS + hd))*NTOK + t)*HC + cc) = st;
        }
      }
    }
  }
}

// ---------------------------------------------------------------------------
// K2: MFMA flash attention (R13: V staged once per block in padded LDS).
// ---------------------------------------------------------------------------
__global__ __launch_bounds__(256)
void k_attn(const u16* __restrict__ qkv, const float* __restrict__ rpe,
            u16* __restrict__ athi) {
  const int win = blockIdx.x;
  const int head = blockIdx.y;
  const int tid = threadIdx.x;
  const int wave = tid >> 6;
  const int lane = tid & 63;
  const int u = lane & 15;
  const int g = lane >> 4;

  __shared__ float lrpe[RPE_N];
  __shared__ u16 vls[32*VLP];    // V [c][t+pad], 16.5KB

  const size_t wh = (size_t)(win*HEADS + head);
  const u16* qp = qkv + wh*NTOK*HC;
  const u16* kp = qkv + SLABSZ + wh*NTOK*HC;
  const u16* vp = qkv + 2*SLABSZ + wh*HC*NTOK;

  for (int i = tid; i < RPE_N; i += 256) lrpe[i] = rpe[head*RPE_N + i];
  #pragma unroll
  for (int i = 0; i < 4; ++i) {
    const int flat = i*256 + tid;     // 0..1023
    const int c = flat >> 5;          // 0..31
    const int ck = flat & 31;         // 16B chunk within row
    const s16x8 v8 = *reinterpret_cast<const s16x8*>(vp + (size_t)c*NTOK + ck*8);
    *reinterpret_cast<s16x8*>(&vls[(size_t)c*VLP + ck*8]) = v8;
  }
  __syncthreads();

  s16x8 qf[4];
  #pragma unroll
  for (int qt = 0; qt < 4; ++qt)
    qf[qt] = *reinterpret_cast<const s16x8*>(qp + (wave*64 + qt*16 + u)*HC + g*8);

  f32x4 oacc[2][4];
  float m[4], l[4];
  #pragma unroll
  for (int qt = 0; qt < 4; ++qt) {
    m[qt] = -INFINITY; l[qt] = 0.f;
    #pragma unroll
    for (int ct = 0; ct < 2; ++ct) oacc[ct][qt] = (f32x4){0.f,0.f,0.f,0.f};
  }
  const float scale = 0.17677669529663687f;  // 1/sqrt(32)

  #pragma unroll 1
  for (int ch = 0; ch < 8; ++ch) {
    const int t0 = ch*32;
    const s16x8 kf0 = *reinterpret_cast<const s16x8*>(kp + (t0 + u)*HC + g*8);
    const s16x8 kf1 = *reinterpret_cast<const s16x8*>(kp + (t0 + 16 + u)*HC + g*8);
    s16x8 vf[2];
    #pragma unroll
    for (int ct = 0; ct < 2; ++ct) {
      const int c = ct*16 + u;
      const ushort4 lo = *reinterpret_cast<const ushort4*>(&vls[(size_t)c*VLP + t0 + g*4]);
      const ushort4 hi = *reinterpret_cast<const ushort4*>(&vls[(size_t)c*VLP + t0 + 16 + g*4]);
      s16x8 v;
      v[0]=(short)lo.x; v[1]=(short)lo.y; v[2]=(short)lo.z; v[3]=(short)lo.w;
      v[4]=(short)hi.x; v[5]=(short)hi.y; v[6]=(short)hi.z; v[7]=(short)hi.w;
      vf[ct] = v;
    }
    const f32x4 zero = {0.f,0.f,0.f,0.f};
    f32x4 s0[4], s1[4];
    #pragma unroll
    for (int qt = 0; qt < 4; ++qt) {
      s0[qt] = __builtin_amdgcn_mfma_f32_16x16x32_bf16(kf0, qf[qt], zero, 0, 0, 0);
      s1[qt] = __builtin_amdgcn_mfma_f32_16x16x32_bf16(kf1, qf[qt], zero, 0, 0, 0);
    }
    #pragma unroll
    for (int qt = 0; qt < 4; ++qt) {
      const int qh = wave*4 + qt;
      const float* r0 = &lrpe[(ch*2 + 0 - qh + 15)*31 + g*4 + 15 - u];
      const float* r1 = &lrpe[(ch*2 + 1 - qh + 15)*31 + g*4 + 15 - u];
      float p0[4], p1[4];
      #pragma unroll
      for (int r = 0; r < 4; ++r) {
        p0[r] = fmaf(s0[qt][r], scale, r0[r]);
        p1[r] = fmaf(s1[qt][r], scale, r1[r]);
      }
      float mt = fmaxf(fmaxf(fmaxf(p0[0],p0[1]), fmaxf(p0[2],p0[3])),
                       fmaxf(fmaxf(p1[0],p1[1]), fmaxf(p1[2],p1[3])));
      mt = fmaxf(mt, __shfl_xor(mt, 16));
      mt = fmaxf(mt, __shfl_xor(mt, 32));
      const float mnew = fmaxf(m[qt], mt);
      const float f = __expf(m[qt] - mnew);
      m[qt] = mnew;
      float ls = 0.f;
      #pragma unroll
      for (int r = 0; r < 4; ++r) {
        p0[r] = __expf(p0[r] - mnew); ls += p0[r];
        p1[r] = __expf(p1[r] - mnew); ls += p1[r];
      }
      ls += __shfl_xor(ls, 16);
      ls += __shfl_xor(ls, 32);
      l[qt] = l[qt]*f + ls;
      #pragma unroll
      for (int ct = 0; ct < 2; ++ct)
        #pragma unroll
        for (int r = 0; r < 4; ++r) oacc[ct][qt][r] *= f;
      s16x8 pf;
      pf[0]=(short)f2bf(p0[0]); pf[1]=(short)f2bf(p0[1]);
      pf[2]=(short)f2bf(p0[2]); pf[3]=(short)f2bf(p0[3]);
      pf[4]=(short)f2bf(p1[0]); pf[5]=(short)f2bf(p1[1]);
      pf[6]=(short)f2bf(p1[2]); pf[7]=(short)f2bf(p1[3]);
      oacc[0][qt] = __builtin_amdgcn_mfma_f32_16x16x32_bf16(vf[0], pf, oacc[0][qt], 0, 0, 0);
      oacc[1][qt] = __builtin_amdgcn_mfma_f32_16x16x32_bf16(vf[1], pf, oacc[1][qt], 0, 0, 0);
    }
  }

  const int b = win / NWIN_B, wl = win % NWIN_B;
  const int h0 = (wl / WDq) * 16;
  const int w = (wl % WDq) * 16 + u;
  #pragma unroll
  for (int qt = 0; qt < 4; ++qt) {
    const float inv = 1.f / l[qt];
    const int h = h0 + wave*4 + qt;
    const size_t row = (size_t)b*NPIX + (size_t)h*WIMG + w;
    #pragma unroll
    for (int ct = 0; ct < 2; ++ct) {
      const int c0 = head*HC + ct*16 + g*4;
      ushort4 vh;
      vh.x = f2bf(oacc[ct][qt][0]*inv);
      vh.y = f2bf(oacc[ct][qt][1]*inv);
      vh.z = f2bf(oacc[ct][qt][2]*inv);
      vh.w = f2bf(oacc[ct][qt][3]*inv);
      *reinterpret_cast<ushort4*>(athi + row*DIM + c0) = vh;
    }
  }
}

// ---------------------------------------------------------------------------
// K3: out = w_out @ attn + b_out, 2-term split MFMA, single-stage, A from
// fragment-ordered W (ot 36..47).
// ---------------------------------------------------------------------------
__global__ __launch_bounds__(256, 3)
void k_proj_mfma(const u16* __restrict__ at, const u16* __restrict__ whiF,
                 const u16* __restrict__ wloF, const float* __restrict__ bout,
                 float* __restrict__ out) {
  const size_t P0 = (size_t)blockIdx.x * 64;
  const int tid = threadIdx.x;
  const int wave = tid >> 6, lane = tid & 63;
  const int u = lane & 15, g = lane >> 4;
  const int o_w = wave * 48;

  __shared__ u16 lb[3][4096];

  f32x4 acc[3][4];
  #pragma unroll
  for (int of = 0; of < 3; ++of)
    #pragma unroll
    for (int hf = 0; hf < 4; ++hf) acc[of][hf] = (f32x4){0.f,0.f,0.f,0.f};

  const int otb = 36 + wave*3;   // w_out fragment tiles

  #pragma unroll
  for (int c = 0; c < 3; ++c)
    #pragma unroll
    for (int rep = 0; rep < 2; ++rep) {
      const int s = (rep*4 + wave)*64 + lane;
      const int row = s >> 3, chl = s & 7;
      gll16(at + (P0 + row)*DIM + c*64 + ((chl ^ (row & 7)) * 8),
            &lb[c][(size_t)((rep*4 + wave)*64) * 8]);
    }

  asm volatile("s_waitcnt vmcnt(0)" ::: "memory");
  __builtin_amdgcn_s_barrier();

  #pragma unroll
  for (int ks = 0; ks < 6; ++ks) {
    s16x8 ah[3], al[3], bh[4];
    #pragma unroll
    for (int of = 0; of < 3; ++of) {
      const size_t fo = (size_t)(((otb + of)*6 + ks) << 9) + (lane << 3);
      ah[of] = *reinterpret_cast<const s16x8*>(whiF + fo);
      al[of] = *reinterpret_cast<const s16x8*>(wloF + fo);
    }
    #pragma unroll
    for (int hf = 0; hf < 4; ++hf) {
      const int row = hf*16 + u;
      const int ch = ((ks & 1)*4 + g) ^ (row & 7);
      bh[hf] = *reinterpret_cast<const s16x8*>(&lb[ks >> 1][row*64 + ch*8]);
    }
    #pragma unroll
    for (int of = 0; of < 3; ++of)
      #pragma unroll
      for (int hf = 0; hf < 4; ++hf)
        acc[of][hf] = __builtin_amdgcn_mfma_f32_16x16x32_bf16(ah[of], bh[hf], acc[of][hf], 0, 0, 0);
    #pragma unroll
    for (int of = 0; of < 3; ++of)
      #pragma unroll
      for (int hf = 0; hf < 4; ++hf)
        acc[of][hf] = __builtin_amdgcn_mfma_f32_16x16x32_bf16(al[of], bh[hf], acc[of][hf], 0, 0, 0);
  }

  #pragma unroll
  for (int of = 0; of < 3; ++of) {
    const int ob = o_w + of*16 + g*4;
    const float4 bias = *reinterpret_cast<const float4*>(bout + ob);
    const float bb[4] = {bias.x, bias.y, bias.z, bias.w};
    #pragma unroll
    for (int hf = 0; hf < 4; ++hf) {
      const size_t pix = P0 + hf*16 + u;
      const int b = (int)(pix / NPIX);
      const int p = (int)(pix % NPIX);
      #pragma unroll
      for (int r = 0; r < 4; ++r)
        out[((size_t)(b*DIM + ob + r))*NPIX + p] = acc[of][hf][r] + bb[r];
    }
  }
}

extern "C" void kernel_launch(void* const* d_in, const int* in_sizes, int n_in,
                              void* d_out, int out_size, void* d_ws, size_t ws_size,
                              hipStream_t stream) {
  const float* x    = (const float*)d_in[0];
  const float* wqkv = (const float*)d_in[1];
  const float* bqkv = (const float*)d_in[2];
  const float* rpe  = (const float*)d_in[3];
  const float* wout = (const float*)d_in[4];
  const float* bout = (const float*)d_in[5];
  float* out = (float*)d_out;

  u16* xhi  = (u16*)d_ws;
  u16* whiF = xhi + XSP_E;
  u16* wloF = whiF + WSP_E;
  u16* qkv  = wloF + WSP_E;           // 3 * SLABSZ bf16
  u16* athi = qkv + 3*SLABSZ;
  // total: 5*XSP_E + 2*WSP_E u16 = 142 MB

  k_xsplit<<<dim3(NPIXT/64), 256, 0, stream>>>(x, xhi);
  k_wsplit<<<dim3(72), 256, 0, stream>>>(wqkv, wout, whiF, wloF);

  k_qkv_mfma<<<dim3(NPIXT/64), 256, 0, stream>>>(xhi, whiF, wloF, bqkv, qkv);

  dim3 g2(NWIN, HEADS);
  k_attn<<<g2, 256, 0, stream>>>(qkv, rpe, athi);

  k_proj_mfma<<<dim3(NPIXT/64), 256, 0, stream>>>(athi, whiF, wloF, bout, out);
}

// Round 15
// 144.712 us; speedup vs baseline: 1.4575x; 1.4575x over previous
//
#include <hip/hip_runtime.h>
#include <math.h>

#define BATCH 2
#define DIM 192
#define HIMG 192
#define WIMG 192
#define NPIX (HIMG*WIMG)      // 36864
#define NPIXT ((size_t)BATCH*NPIX) // 73728 total pixel rows
#define HEADS 6
#define HC 32
#define NTOK 256
#define WDq 12
#define NWIN_B 144
#define NWIN (BATCH*NWIN_B)   // 288
#define RPE_N 961
#define SLABSZ ((size_t)NWIN*HEADS*NTOK*HC)   // 14,155,776 elems per q/k/v slab
#define XSP_E ((size_t)NPIXT*DIM)             // 14,155,776 u16 per split array
#define WSP_E ((size_t)(3*DIM+DIM)*DIM)       // 147,456 u16 (fragment-ordered)
#define VLP 264                                // k_attn V-stage row stride (u16)

typedef float f32x4 __attribute__((ext_vector_type(4)));
typedef short s16x8 __attribute__((ext_vector_type(8)));
typedef unsigned short u16;

__device__ __forceinline__ u16 f2bf(float f) {
  union { float f; unsigned u; } cv; cv.f = f;
  unsigned u = cv.u + 0x7fffu + ((cv.u >> 16) & 1u);   // RNE
  return (u16)(u >> 16);
}
__device__ __forceinline__ float bf2f(u16 h) {
  union { unsigned u; float f; } cv; cv.u = ((unsigned)h) << 16;
  return cv.f;
}
__device__ __forceinline__ void split2(float f, u16& hi, u16& lo) {
  hi = f2bf(f);
  lo = f2bf(f - bf2f(hi));
}
// async global->LDS, 16B per lane. LDS dest is wave-uniform base + lane*16.
__device__ __forceinline__ void gll16(const void* g, void* l) {
  __builtin_amdgcn_global_load_lds(
      (const __attribute__((address_space(1))) void*)g,
      (__attribute__((address_space(3))) void*)l, 16, 0, 0);
}

// ---------------------------------------------------------------------------
// T0: transpose x [b][c][pix] fp32 -> xT bf16 [b*pix][c] (float4 reads).
// ---------------------------------------------------------------------------
__global__ __launch_bounds__(256)
void k_xsplit(const float* __restrict__ x, u16* __restrict__ xhi) {
  const size_t P0 = (size_t)blockIdx.x * 64;
  const int b = (int)(P0 / NPIX);
  const int p0 = (int)(P0 % NPIX);
  __shared__ float lds[DIM][65];
  const int tid = threadIdx.x;
  const float* xb = x + (size_t)b*DIM*NPIX + p0;
  #pragma unroll
  for (int i = 0; i < 12; ++i) {
    const int idx = i*256 + tid;          // 0..3071
    const int c = idx >> 4;               // 0..191
    const int p4 = (idx & 15) << 2;       // 0..60
    const float4 v4 = *reinterpret_cast<const float4*>(xb + (size_t)c*NPIX + p4);
    lds[c][p4+0] = v4.x;
    lds[c][p4+1] = v4.y;
    lds[c][p4+2] = v4.z;
    lds[c][p4+3] = v4.w;
  }
  __syncthreads();
  const int wave = tid >> 6, lane = tid & 63;
  if (lane < 48) {
    const int c0 = lane * 4;
    #pragma unroll
    for (int rr = 0; rr < 16; ++rr) {
      const int p = wave*16 + rr;
      ushort4 vh;
      vh.x = f2bf(lds[c0+0][p]);
      vh.y = f2bf(lds[c0+1][p]);
      vh.z = f2bf(lds[c0+2][p]);
      vh.w = f2bf(lds[c0+3][p]);
      *reinterpret_cast<ushort4*>(xhi + (P0 + p)*DIM + c0) = vh;
    }
  }
}

// ---------------------------------------------------------------------------
// T1: split w_qkv/w_out into hi/lo u16 in MFMA-FRAGMENT order:
//   frag[(ot*6 + ks)*512 + lane*8 + i]  <->  w[row=ot*16+(lane&15)]
//                                             [k=ks*32+(lane>>4)*8+i]
// One A-fragment load = one fully-coalesced 1KB wave load (was a 16-line
// gather at 384B row stride). ot 0..35 = wqkv, 36..47 = wout.
// ---------------------------------------------------------------------------
__global__ __launch_bounds__(256)
void k_wsplit(const float* __restrict__ wqkv, const float* __restrict__ wout,
              u16* __restrict__ whi, u16* __restrict__ wlo) {
  const int gid = blockIdx.x*256 + threadIdx.x;      // 0..18431
  const int ot = gid / 384;
  const int rem = gid - ot*384;
  const int ks = rem >> 6;
  const int lane = rem & 63;
  const int u = lane & 15, g = lane >> 4;
  const int row = ot*16 + u;
  const float* src = (row < 3*DIM) ? (wqkv + (size_t)row*DIM + ks*32 + g*8)
                                   : (wout + (size_t)(row - 3*DIM)*DIM + ks*32 + g*8);
  const float4 a = *reinterpret_cast<const float4*>(src);
  const float4 b = *reinterpret_cast<const float4*>(src + 4);
  const float fv[8] = {a.x, a.y, a.z, a.w, b.x, b.y, b.z, b.w};
  s16x8 vh, vl;
  #pragma unroll
  for (int i = 0; i < 8; ++i) {
    u16 h, l;
    split2(fv[i], h, l);
    vh[i] = (short)h; vl[i] = (short)l;
  }
  *reinterpret_cast<s16x8*>(whi + (size_t)gid*8) = vh;
  *reinterpret_cast<s16x8*>(wlo + (size_t)gid*8) = vl;
}

// ---------------------------------------------------------------------------
// K1: qkv = w_qkv @ x + b_qkv, 2-term split MFMA (w hi/lo, x bf16).
// R13 structure EXACTLY (grid 3456, XCD-sibling swizzle, per-slab blocks,
// single-stage, rotating 2-ahead A prefetch). R15 sole change: A loads use
// the fragment-ordered W (coalesced 1KB wave loads).
// ---------------------------------------------------------------------------
__global__ __launch_bounds__(256, 3)
void k_qkv_mfma(const u16* __restrict__ xhi,
                const u16* __restrict__ whiF, const u16* __restrict__ wloF,
                const float* __restrict__ bqkv, u16* __restrict__ qkv) {
  const int id = blockIdx.x;                 // 0..3455
  const int slot = id & 7;
  const int grp = id >> 3;                   // 0..431
  const int slab = grp % 3;
  const size_t P0 = (size_t)(slot + 8*(grp/3)) * 64;
  const int tid = threadIdx.x;
  const int wave = tid >> 6, lane = tid & 63;
  const int u = lane & 15, g = lane >> 4;
  const int o_w = wave * 48;                 // 4 waves cover 192 o

  // [chunk][64 rows x 64 k-elems] bf16, 8KB per plane, 24KB total
  __shared__ u16 lb[3][4096];

  f32x4 acc[3][4];
  #pragma unroll
  for (int of = 0; of < 3; ++of)
    #pragma unroll
    for (int hf = 0; hf < 4; ++hf) acc[of][hf] = (f32x4){0.f,0.f,0.f,0.f};

  // fragment-ordered A base for this wave's 3 row-tiles
  const int otb = slab*12 + wave*3;
  #define AFO(of, ks) ((size_t)(((otb + (of))*6 + (ks)) << 9) + (lane << 3))

  // stage ALL 3 chunks (global source pre-swizzled, LDS dest linear; read
  // applies the same XOR involution -> conflict-free ds_read_b128)
  #pragma unroll
  for (int c = 0; c < 3; ++c)
    #pragma unroll
    for (int rep = 0; rep < 2; ++rep) {
      const int s = (rep*4 + wave)*64 + lane;
      const int row = s >> 3, chl = s & 7;
      gll16(xhi + (P0 + row)*DIM + c*64 + ((chl ^ (row & 7)) * 8),
            &lb[c][(size_t)((rep*4 + wave)*64) * 8]);
    }

  // A prefetch: 3 rotating sets, 2-ahead
  s16x8 Ah[3][3], Al[3][3];
  #pragma unroll
  for (int p = 0; p < 2; ++p)
    #pragma unroll
    for (int of = 0; of < 3; ++of) {
      Ah[p][of] = *reinterpret_cast<const s16x8*>(whiF + AFO(of, p));
      Al[p][of] = *reinterpret_cast<const s16x8*>(wloF + AFO(of, p));
    }

  asm volatile("s_waitcnt vmcnt(0)" ::: "memory");   // stage + A0/A1 done
  __builtin_amdgcn_s_barrier();                      // the only barrier

  #pragma unroll
  for (int ks = 0; ks < 6; ++ks) {
    if (ks < 4) {
      const int pn = (ks + 2) % 3;                   // compile-time after unroll
      #pragma unroll
      for (int of = 0; of < 3; ++of) {
        Ah[pn][of] = *reinterpret_cast<const s16x8*>(whiF + AFO(of, ks+2));
        Al[pn][of] = *reinterpret_cast<const s16x8*>(wloF + AFO(of, ks+2));
      }
    }
    s16x8 bh[4];
    #pragma unroll
    for (int hf = 0; hf < 4; ++hf) {
      const int row = hf*16 + u;
      const int ch = ((ks & 1)*4 + g) ^ (row & 7);
      bh[hf] = *reinterpret_cast<const s16x8*>(&lb[ks >> 1][row*64 + ch*8]);
    }
    const int p = ks % 3;
    #pragma unroll
    for (int of = 0; of < 3; ++of)
      #pragma unroll
      for (int hf = 0; hf < 4; ++hf) {
        acc[of][hf] = __builtin_amdgcn_mfma_f32_16x16x32_bf16(Ah[p][of], bh[hf], acc[of][hf], 0, 0, 0);
        acc[of][hf] = __builtin_amdgcn_mfma_f32_16x16x32_bf16(Al[p][of], bh[hf], acc[of][hf], 0, 0, 0);
      }
  }
  #undef AFO

  // epilogue: windowed scatter, bf16
  u16* base = qkv + (size_t)slab * SLABSZ;
  const float* bq = bqkv + slab*DIM;
  #pragma unroll
  for (int of = 0; of < 3; ++of) {
    const int ob = o_w + of*16 + g*4;        // 4 consecutive o (+r)
    const int hd = ob >> 5, cc = ob & 31;
    const float4 bias = *reinterpret_cast<const float4*>(bq + ob);
    #pragma unroll
    for (int hf = 0; hf < 4; ++hf) {
      const size_t pix = P0 + hf*16 + u;
      const int b = (int)(pix / NPIX);
      const int p = (int)(pix % NPIX);
      const int h = p / WIMG, w = p % WIMG;
      const int win = b*NWIN_B + (h >> 4)*WDq + (w >> 4);
      const int t = (h & 15)*16 + (w & 15);
      const float v0 = acc[of][hf][0] + bias.x;
      const float v1 = acc[of][hf][1] + bias.y;
      const float v2 = acc[of][hf][2] + bias.z;
      const float v3 = acc[of][hf][3] + bias.w;
      if (slab == 2) {
        u16* p2 = base + (((size_t)(win*HEADS + hd))*HC + cc)*NTOK + t;
        p2[0*NTOK] = f2bf(v0);
        p2[1*NTOK] = f2bf(v1);
        p2[2*NTOK] = f2bf(v2);
        p2[3*NTOK] = f2bf(v3);
      } else {
        ushort4 st;
        st.x = f2bf(v0); st.y = f2bf(v1); st.z = f2bf(v2); st.w = f2bf(v3);
        *reinterpret_cast<ushort4*>(base + (((size_t)(win*HEADS + hd))*NTOK + t)*HC + cc) = st;
      }
    }
  }
}

// ---------------------------------------------------------------------------
// K2: MFMA flash attention (R13: V staged once per block in padded LDS).
// ---------------------------------------------------------------------------
__global__ __launch_bounds__(256)
void k_attn(const u16* __restrict__ qkv, const float* __restrict__ rpe,
            u16* __restrict__ athi) {
  const int win = blockIdx.x;
  const int head = blockIdx.y;
  const int tid = threadIdx.x;
  const int wave = tid >> 6;
  const int lane = tid & 63;
  const int u = lane & 15;
  const int g = lane >> 4;

  __shared__ float lrpe[RPE_N];
  __shared__ u16 vls[32*VLP];    // V [c][t+pad], 16.5KB

  const size_t wh = (size_t)(win*HEADS + head);
  const u16* qp = qkv + wh*NTOK*HC;
  const u16* kp = qkv + SLABSZ + wh*NTOK*HC;
  const u16* vp = qkv + 2*SLABSZ + wh*HC*NTOK;

  for (int i = tid; i < RPE_N; i += 256) lrpe[i] = rpe[head*RPE_N + i];
  #pragma unroll
  for (int i = 0; i < 4; ++i) {
    const int flat = i*256 + tid;     // 0..1023
    const int c = flat >> 5;          // 0..31
    const int ck = flat & 31;         // 16B chunk within row
    const s16x8 v8 = *reinterpret_cast<const s16x8*>(vp + (size_t)c*NTOK + ck*8);
    *reinterpret_cast<s16x8*>(&vls[(size_t)c*VLP + ck*8]) = v8;
  }
  __syncthreads();

  s16x8 qf[4];
  #pragma unroll
  for (int qt = 0; qt < 4; ++qt)
    qf[qt] = *reinterpret_cast<const s16x8*>(qp + (wave*64 + qt*16 + u)*HC + g*8);

  f32x4 oacc[2][4];
  float m[4], l[4];
  #pragma unroll
  for (int qt = 0; qt < 4; ++qt) {
    m[qt] = -INFINITY; l[qt] = 0.f;
    #pragma unroll
    for (int ct = 0; ct < 2; ++ct) oacc[ct][qt] = (f32x4){0.f,0.f,0.f,0.f};
  }
  const float scale = 0.17677669529663687f;  // 1/sqrt(32)

  #pragma unroll 1
  for (int ch = 0; ch < 8; ++ch) {
    const int t0 = ch*32;
    const s16x8 kf0 = *reinterpret_cast<const s16x8*>(kp + (t0 + u)*HC + g*8);
    const s16x8 kf1 = *reinterpret_cast<const s16x8*>(kp + (t0 + 16 + u)*HC + g*8);
    s16x8 vf[2];
    #pragma unroll
    for (int ct = 0; ct < 2; ++ct) {
      const int c = ct*16 + u;
      const ushort4 lo = *reinterpret_cast<const ushort4*>(&vls[(size_t)c*VLP + t0 + g*4]);
      const ushort4 hi = *reinterpret_cast<const ushort4*>(&vls[(size_t)c*VLP + t0 + 16 + g*4]);
      s16x8 v;
      v[0]=(short)lo.x; v[1]=(short)lo.y; v[2]=(short)lo.z; v[3]=(short)lo.w;
      v[4]=(short)hi.x; v[5]=(short)hi.y; v[6]=(short)hi.z; v[7]=(short)hi.w;
      vf[ct] = v;
    }
    const f32x4 zero = {0.f,0.f,0.f,0.f};
    f32x4 s0[4], s1[4];
    #pragma unroll
    for (int qt = 0; qt < 4; ++qt) {
      s0[qt] = __builtin_amdgcn_mfma_f32_16x16x32_bf16(kf0, qf[qt], zero, 0, 0, 0);
      s1[qt] = __builtin_amdgcn_mfma_f32_16x16x32_bf16(kf1, qf[qt], zero, 0, 0, 0);
    }
    #pragma unroll
    for (int qt = 0; qt < 4; ++qt) {
      const int qh = wave*4 + qt;
      const float* r0 = &lrpe[(ch*2 + 0 - qh + 15)*31 + g*4 + 15 - u];
      const float* r1 = &lrpe[(ch*2 + 1 - qh + 15)*31 + g*4 + 15 - u];
      float p0[4], p1[4];
      #pragma unroll
      for (int r = 0; r < 4; ++r) {
        p0[r] = fmaf(s0[qt][r], scale, r0[r]);
        p1[r] = fmaf(s1[qt][r], scale, r1[r]);
      }
      float mt = fmaxf(fmaxf(fmaxf(p0[0],p0[1]), fmaxf(p0[2],p0[3])),
                       fmaxf(fmaxf(p1[0],p1[1]), fmaxf(p1[2],p1[3])));
      mt = fmaxf(mt, __shfl_xor(mt, 16));
      mt = fmaxf(mt, __shfl_xor(mt, 32));
      const float mnew = fmaxf(m[qt], mt);
      const float f = __expf(m[qt] - mnew);
      m[qt] = mnew;
      float ls = 0.f;
      #pragma unroll
      for (int r = 0; r < 4; ++r) {
        p0[r] = __expf(p0[r] - mnew); ls += p0[r];
        p1[r] = __expf(p1[r] - mnew); ls += p1[r];
      }
      ls += __shfl_xor(ls, 16);
      ls += __shfl_xor(ls, 32);
      l[qt] = l[qt]*f + ls;
      #pragma unroll
      for (int ct = 0; ct < 2; ++ct)
        #pragma unroll
        for (int r = 0; r < 4; ++r) oacc[ct][qt][r] *= f;
      s16x8 pf;
      pf[0]=(short)f2bf(p0[0]); pf[1]=(short)f2bf(p0[1]);
      pf[2]=(short)f2bf(p0[2]); pf[3]=(short)f2bf(p0[3]);
      pf[4]=(short)f2bf(p1[0]); pf[5]=(short)f2bf(p1[1]);
      pf[6]=(short)f2bf(p1[2]); pf[7]=(short)f2bf(p1[3]);
      oacc[0][qt] = __builtin_amdgcn_mfma_f32_16x16x32_bf16(vf[0], pf, oacc[0][qt], 0, 0, 0);
      oacc[1][qt] = __builtin_amdgcn_mfma_f32_16x16x32_bf16(vf[1], pf, oacc[1][qt], 0, 0, 0);
    }
  }

  const int b = win / NWIN_B, wl = win % NWIN_B;
  const int h0 = (wl / WDq) * 16;
  const int w = (wl % WDq) * 16 + u;
  #pragma unroll
  for (int qt = 0; qt < 4; ++qt) {
    const float inv = 1.f / l[qt];
    const int h = h0 + wave*4 + qt;
    const size_t row = (size_t)b*NPIX + (size_t)h*WIMG + w;
    #pragma unroll
    for (int ct = 0; ct < 2; ++ct) {
      const int c0 = head*HC + ct*16 + g*4;
      ushort4 vh;
      vh.x = f2bf(oacc[ct][qt][0]*inv);
      vh.y = f2bf(oacc[ct][qt][1]*inv);
      vh.z = f2bf(oacc[ct][qt][2]*inv);
      vh.w = f2bf(oacc[ct][qt][3]*inv);
      *reinterpret_cast<ushort4*>(athi + row*DIM + c0) = vh;
    }
  }
}

// ---------------------------------------------------------------------------
// K3: out = w_out @ attn + b_out, 2-term split MFMA, single-stage (R13),
// A from fragment-ordered W (ot 36..47).
// ---------------------------------------------------------------------------
__global__ __launch_bounds__(256, 3)
void k_proj_mfma(const u16* __restrict__ at, const u16* __restrict__ whiF,
                 const u16* __restrict__ wloF, const float* __restrict__ bout,
                 float* __restrict__ out) {
  const size_t P0 = (size_t)blockIdx.x * 64;
  const int tid = threadIdx.x;
  const int wave = tid >> 6, lane = tid & 63;
  const int u = lane & 15, g = lane >> 4;
  const int o_w = wave * 48;

  __shared__ u16 lb[3][4096];

  f32x4 acc[3][4];
  #pragma unroll
  for (int of = 0; of < 3; ++of)
    #pragma unroll
    for (int hf = 0; hf < 4; ++hf) acc[of][hf] = (f32x4){0.f,0.f,0.f,0.f};

  const int otb = 36 + wave*3;   // w_out fragment tiles
  #define AFO3(of, ks) ((size_t)(((otb + (of))*6 + (ks)) << 9) + (lane << 3))

  #pragma unroll
  for (int c = 0; c < 3; ++c)
    #pragma unroll
    for (int rep = 0; rep < 2; ++rep) {
      const int s = (rep*4 + wave)*64 + lane;
      const int row = s >> 3, chl = s & 7;
      gll16(at + (P0 + row)*DIM + c*64 + ((chl ^ (row & 7)) * 8),
            &lb[c][(size_t)((rep*4 + wave)*64) * 8]);
    }

  s16x8 Ah[3][3], Al[3][3];
  #pragma unroll
  for (int p = 0; p < 2; ++p)
    #pragma unroll
    for (int of = 0; of < 3; ++of) {
      Ah[p][of] = *reinterpret_cast<const s16x8*>(whiF + AFO3(of, p));
      Al[p][of] = *reinterpret_cast<const s16x8*>(wloF + AFO3(of, p));
    }

  asm volatile("s_waitcnt vmcnt(0)" ::: "memory");
  __builtin_amdgcn_s_barrier();

  #pragma unroll
  for (int ks = 0; ks < 6; ++ks) {
    if (ks < 4) {
      const int pn = (ks + 2) % 3;
      #pragma unroll
      for (int of = 0; of < 3; ++of) {
        Ah[pn][of] = *reinterpret_cast<const s16x8*>(whiF + AFO3(of, ks+2));
        Al[pn][of] = *reinterpret_cast<const s16x8*>(wloF + AFO3(of, ks+2));
      }
    }
    s16x8 bh[4];
    #pragma unroll
    for (int hf = 0; hf < 4; ++hf) {
      const int row = hf*16 + u;
      const int ch = ((ks & 1)*4 + g) ^ (row & 7);
      bh[hf] = *reinterpret_cast<const s16x8*>(&lb[ks >> 1][row*64 + ch*8]);
    }
    const int p = ks % 3;
    #pragma unroll
    for (int of = 0; of < 3; ++of)
      #pragma unroll
      for (int hf = 0; hf < 4; ++hf) {
        acc[of][hf] = __builtin_amdgcn_mfma_f32_16x16x32_bf16(Ah[p][of], bh[hf], acc[of][hf], 0, 0, 0);
        acc[of][hf] = __builtin_amdgcn_mfma_f32_16x16x32_bf16(Al[p][of], bh[hf], acc[of][hf], 0, 0, 0);
      }
  }
  #undef AFO3

  #pragma unroll
  for (int of = 0; of < 3; ++of) {
    const int ob = o_w + of*16 + g*4;
    const float4 bias = *reinterpret_cast<const float4*>(bout + ob);
    const float bb[4] = {bias.x, bias.y, bias.z, bias.w};
    #pragma unroll
    for (int hf = 0; hf < 4; ++hf) {
      const size_t pix = P0 + hf*16 + u;
      const int b = (int)(pix / NPIX);
      const int p = (int)(pix % NPIX);
      #pragma unroll
      for (int r = 0; r < 4; ++r)
        out[((size_t)(b*DIM + ob + r))*NPIX + p] = acc[of][hf][r] + bb[r];
    }
  }
}

extern "C" void kernel_launch(void* const* d_in, const int* in_sizes, int n_in,
                              void* d_out, int out_size, void* d_ws, size_t ws_size,
                              hipStream_t stream) {
  const float* x    = (const float*)d_in[0];
  const float* wqkv = (const float*)d_in[1];
  const float* bqkv = (const float*)d_in[2];
  const float* rpe  = (const float*)d_in[3];
  const float* wout = (const float*)d_in[4];
  const float* bout = (const float*)d_in[5];
  float* out = (float*)d_out;

  u16* xhi  = (u16*)d_ws;
  u16* whiF = xhi + XSP_E;
  u16* wloF = whiF + WSP_E;
  u16* qkv  = wloF + WSP_E;           // 3 * SLABSZ bf16
  u16* athi = qkv + 3*SLABSZ;
  // total: 5*XSP_E + 2*WSP_E u16 = 142 MB

  k_xsplit<<<dim3(NPIXT/64), 256, 0, stream>>>(x, xhi);
  k_wsplit<<<dim3(72), 256, 0, stream>>>(wqkv, wout, whiF, wloF);

  // 3456 blocks: slab-siblings of each pix tile share id%8 => same XCD
  k_qkv_mfma<<<dim3(3*NPIXT/64), 256, 0, stream>>>(xhi, whiF, wloF, bqkv, qkv);

  dim3 g2(NWIN, HEADS);
  k_attn<<<g2, 256, 0, stream>>>(qkv, rpe, athi);

  k_proj_mfma<<<dim3(NPIXT/64), 256, 0, stream>>>(athi, whiF, wloF, bout, out);
}

// Round 16
// 140.358 us; speedup vs baseline: 1.5027x; 1.0310x over previous
//
#include <hip/hip_runtime.h>
#include <math.h>

#define BATCH 2
#define DIM 192
#define HIMG 192
#define WIMG 192
#define NPIX (HIMG*WIMG)      // 36864
#define NPIXT ((size_t)BATCH*NPIX) // 73728 total pixel rows
#define HEADS 6
#define HC 32
#define NTOK 256
#define WDq 12
#define NWIN_B 144
#define NWIN (BATCH*NWIN_B)   // 288
#define RPE_N 961
#define SLABSZ ((size_t)NWIN*HEADS*NTOK*HC)   // 14,155,776 elems per q/k/v slab
#define XSP_E ((size_t)NPIXT*DIM)             // 14,155,776 u16 per split array
#define WSP_E ((size_t)(3*DIM+DIM)*DIM)       // 147,456 u16 (fragment-ordered)
#define VLP 264                                // k_attn V-stage row stride (u16)

typedef float f32x4 __attribute__((ext_vector_type(4)));
typedef short s16x8 __attribute__((ext_vector_type(8)));
typedef unsigned short u16;

__device__ __forceinline__ u16 f2bf(float f) {
  union { float f; unsigned u; } cv; cv.f = f;
  unsigned u = cv.u + 0x7fffu + ((cv.u >> 16) & 1u);   // RNE
  return (u16)(u >> 16);
}
__device__ __forceinline__ float bf2f(u16 h) {
  union { unsigned u; float f; } cv; cv.u = ((unsigned)h) << 16;
  return cv.f;
}
__device__ __forceinline__ void split2(float f, u16& hi, u16& lo) {
  hi = f2bf(f);
  lo = f2bf(f - bf2f(hi));
}
// packed f32x2 -> bf16x2 in ONE VALU op (replaces ~9 ops of manual RNE)
__device__ __forceinline__ unsigned cvtpk(float a, float b) {
  unsigned r;
  asm("v_cvt_pk_bf16_f32 %0, %1, %2" : "=v"(r) : "v"(a), "v"(b));
  return r;
}
// async global->LDS, 16B per lane. LDS dest is wave-uniform base + lane*16.
__device__ __forceinline__ void gll16(const void* g, void* l) {
  __builtin_amdgcn_global_load_lds(
      (const __attribute__((address_space(1))) void*)g,
      (__attribute__((address_space(3))) void*)l, 16, 0, 0);
}

// ---------------------------------------------------------------------------
// T0: transpose x [b][c][pix] fp32 -> xT bf16 [b*pix][c] (float4 reads).
// ---------------------------------------------------------------------------
__global__ __launch_bounds__(256)
void k_xsplit(const float* __restrict__ x, u16* __restrict__ xhi) {
  const size_t P0 = (size_t)blockIdx.x * 64;
  const int b = (int)(P0 / NPIX);
  const int p0 = (int)(P0 % NPIX);
  __shared__ float lds[DIM][65];
  const int tid = threadIdx.x;
  const float* xb = x + (size_t)b*DIM*NPIX + p0;
  #pragma unroll
  for (int i = 0; i < 12; ++i) {
    const int idx = i*256 + tid;          // 0..3071
    const int c = idx >> 4;               // 0..191
    const int p4 = (idx & 15) << 2;       // 0..60
    const float4 v4 = *reinterpret_cast<const float4*>(xb + (size_t)c*NPIX + p4);
    lds[c][p4+0] = v4.x;
    lds[c][p4+1] = v4.y;
    lds[c][p4+2] = v4.z;
    lds[c][p4+3] = v4.w;
  }
  __syncthreads();
  const int wave = tid >> 6, lane = tid & 63;
  if (lane < 48) {
    const int c0 = lane * 4;
    #pragma unroll
    for (int rr = 0; rr < 16; ++rr) {
      const int p = wave*16 + rr;
      ushort4 vh;
      vh.x = f2bf(lds[c0+0][p]);
      vh.y = f2bf(lds[c0+1][p]);
      vh.z = f2bf(lds[c0+2][p]);
      vh.w = f2bf(lds[c0+3][p]);
      *reinterpret_cast<ushort4*>(xhi + (P0 + p)*DIM + c0) = vh;
    }
  }
}

// ---------------------------------------------------------------------------
// T1: split w_qkv/w_out into hi/lo u16 in MFMA-FRAGMENT order:
//   frag[(ot*6 + ks)*512 + lane*8 + i]  <->  w[row=ot*16+(lane&15)]
//                                             [k=ks*32+(lane>>4)*8+i]
// One A-fragment load = one fully-coalesced 1KB wave load. ot 0..35 = wqkv,
// 36..47 = wout.
// ---------------------------------------------------------------------------
__global__ __launch_bounds__(256)
void k_wsplit(const float* __restrict__ wqkv, const float* __restrict__ wout,
              u16* __restrict__ whi, u16* __restrict__ wlo) {
  const int gid = blockIdx.x*256 + threadIdx.x;      // 0..18431
  const int ot = gid / 384;
  const int rem = gid - ot*384;
  const int ks = rem >> 6;
  const int lane = rem & 63;
  const int u = lane & 15, g = lane >> 4;
  const int row = ot*16 + u;
  const float* src = (row < 3*DIM) ? (wqkv + (size_t)row*DIM + ks*32 + g*8)
                                   : (wout + (size_t)(row - 3*DIM)*DIM + ks*32 + g*8);
  const float4 a = *reinterpret_cast<const float4*>(src);
  const float4 b = *reinterpret_cast<const float4*>(src + 4);
  const float fv[8] = {a.x, a.y, a.z, a.w, b.x, b.y, b.z, b.w};
  s16x8 vh, vl;
  #pragma unroll
  for (int i = 0; i < 8; ++i) {
    u16 h, l;
    split2(fv[i], h, l);
    vh[i] = (short)h; vl[i] = (short)l;
  }
  *reinterpret_cast<s16x8*>(whi + (size_t)gid*8) = vh;
  *reinterpret_cast<s16x8*>(wlo + (size_t)gid*8) = vl;
}

// ---------------------------------------------------------------------------
// K1: qkv = w_qkv @ x + b_qkv, 2-term split MFMA (w hi/lo, x bf16).
// R15 structure (validated best): grid 3456, XCD-sibling swizzle, per-slab
// blocks, single-stage, rotating 2-ahead A prefetch, fragment-ordered A.
// ---------------------------------------------------------------------------
__global__ __launch_bounds__(256, 3)
void k_qkv_mfma(const u16* __restrict__ xhi,
                const u16* __restrict__ whiF, const u16* __restrict__ wloF,
                const float* __restrict__ bqkv, u16* __restrict__ qkv) {
  const int id = blockIdx.x;                 // 0..3455
  const int slot = id & 7;
  const int grp = id >> 3;                   // 0..431
  const int slab = grp % 3;
  const size_t P0 = (size_t)(slot + 8*(grp/3)) * 64;
  const int tid = threadIdx.x;
  const int wave = tid >> 6, lane = tid & 63;
  const int u = lane & 15, g = lane >> 4;
  const int o_w = wave * 48;                 // 4 waves cover 192 o

  // [chunk][64 rows x 64 k-elems] bf16, 8KB per plane, 24KB total
  __shared__ u16 lb[3][4096];

  f32x4 acc[3][4];
  #pragma unroll
  for (int of = 0; of < 3; ++of)
    #pragma unroll
    for (int hf = 0; hf < 4; ++hf) acc[of][hf] = (f32x4){0.f,0.f,0.f,0.f};

  // fragment-ordered A base for this wave's 3 row-tiles
  const int otb = slab*12 + wave*3;
  #define AFO(of, ks) ((size_t)(((otb + (of))*6 + (ks)) << 9) + (lane << 3))

  // stage ALL 3 chunks (global source pre-swizzled, LDS dest linear; read
  // applies the same XOR involution -> conflict-free ds_read_b128)
  #pragma unroll
  for (int c = 0; c < 3; ++c)
    #pragma unroll
    for (int rep = 0; rep < 2; ++rep) {
      const int s = (rep*4 + wave)*64 + lane;
      const int row = s >> 3, chl = s & 7;
      gll16(xhi + (P0 + row)*DIM + c*64 + ((chl ^ (row & 7)) * 8),
            &lb[c][(size_t)((rep*4 + wave)*64) * 8]);
    }

  // A prefetch: 3 rotating sets, 2-ahead
  s16x8 Ah[3][3], Al[3][3];
  #pragma unroll
  for (int p = 0; p < 2; ++p)
    #pragma unroll
    for (int of = 0; of < 3; ++of) {
      Ah[p][of] = *reinterpret_cast<const s16x8*>(whiF + AFO(of, p));
      Al[p][of] = *reinterpret_cast<const s16x8*>(wloF + AFO(of, p));
    }

  asm volatile("s_waitcnt vmcnt(0)" ::: "memory");   // stage + A0/A1 done
  __builtin_amdgcn_s_barrier();                      // the only barrier

  #pragma unroll
  for (int ks = 0; ks < 6; ++ks) {
    if (ks < 4) {
      const int pn = (ks + 2) % 3;                   // compile-time after unroll
      #pragma unroll
      for (int of = 0; of < 3; ++of) {
        Ah[pn][of] = *reinterpret_cast<const s16x8*>(whiF + AFO(of, ks+2));
        Al[pn][of] = *reinterpret_cast<const s16x8*>(wloF + AFO(of, ks+2));
      }
    }
    s16x8 bh[4];
    #pragma unroll
    for (int hf = 0; hf < 4; ++hf) {
      const int row = hf*16 + u;
      const int ch = ((ks & 1)*4 + g) ^ (row & 7);
      bh[hf] = *reinterpret_cast<const s16x8*>(&lb[ks >> 1][row*64 + ch*8]);
    }
    const int p = ks % 3;
    #pragma unroll
    for (int of = 0; of < 3; ++of)
      #pragma unroll
      for (int hf = 0; hf < 4; ++hf) {
        acc[of][hf] = __builtin_amdgcn_mfma_f32_16x16x32_bf16(Ah[p][of], bh[hf], acc[of][hf], 0, 0, 0);
        acc[of][hf] = __builtin_amdgcn_mfma_f32_16x16x32_bf16(Al[p][of], bh[hf], acc[of][hf], 0, 0, 0);
      }
  }
  #undef AFO

  // epilogue: windowed scatter, bf16
  u16* base = qkv + (size_t)slab * SLABSZ;
  const float* bq = bqkv + slab*DIM;
  #pragma unroll
  for (int of = 0; of < 3; ++of) {
    const int ob = o_w + of*16 + g*4;        // 4 consecutive o (+r)
    const int hd = ob >> 5, cc = ob & 31;
    const float4 bias = *reinterpret_cast<const float4*>(bq + ob);
    #pragma unroll
    for (int hf = 0; hf < 4; ++hf) {
      const size_t pix = P0 + hf*16 + u;
      const int b = (int)(pix / NPIX);
      const int p = (int)(pix % NPIX);
      const int h = p / WIMG, w = p % WIMG;
      const int win = b*NWIN_B + (h >> 4)*WDq + (w >> 4);
      const int t = (h & 15)*16 + (w & 15);
      const float v0 = acc[of][hf][0] + bias.x;
      const float v1 = acc[of][hf][1] + bias.y;
      const float v2 = acc[of][hf][2] + bias.z;
      const float v3 = acc[of][hf][3] + bias.w;
      if (slab == 2) {
        u16* p2 = base + (((size_t)(win*HEADS + hd))*HC + cc)*NTOK + t;
        p2[0*NTOK] = f2bf(v0);
        p2[1*NTOK] = f2bf(v1);
        p2[2*NTOK] = f2bf(v2);
        p2[3*NTOK] = f2bf(v3);
      } else {
        ushort4 st;
        st.x = f2bf(v0); st.y = f2bf(v1); st.z = f2bf(v2); st.w = f2bf(v3);
        *reinterpret_cast<ushort4*>(base + (((size_t)(win*HEADS + hd))*NTOK + t)*HC + cc) = st;
      }
    }
  }
}

// ---------------------------------------------------------------------------
// K2: MFMA flash attention. R16: P->bf16 via v_cvt_pk_bf16_f32 (1 op vs ~9
// of manual RNE) and defer-max RESCALE (skip O/l rescale when the per-tile
// max grows <= 8; wave-uniform branch via __all). V staged in padded LDS.
// ---------------------------------------------------------------------------
__global__ __launch_bounds__(256)
void k_attn(const u16* __restrict__ qkv, const float* __restrict__ rpe,
            u16* __restrict__ athi) {
  const int win = blockIdx.x;
  const int head = blockIdx.y;
  const int tid = threadIdx.x;
  const int wave = tid >> 6;
  const int lane = tid & 63;
  const int u = lane & 15;
  const int g = lane >> 4;

  __shared__ float lrpe[RPE_N];
  __shared__ u16 vls[32*VLP];    // V [c][t+pad], 16.5KB

  const size_t wh = (size_t)(win*HEADS + head);
  const u16* qp = qkv + wh*NTOK*HC;
  const u16* kp = qkv + SLABSZ + wh*NTOK*HC;
  const u16* vp = qkv + 2*SLABSZ + wh*HC*NTOK;

  for (int i = tid; i < RPE_N; i += 256) lrpe[i] = rpe[head*RPE_N + i];
  #pragma unroll
  for (int i = 0; i < 4; ++i) {
    const int flat = i*256 + tid;     // 0..1023
    const int c = flat >> 5;          // 0..31
    const int ck = flat & 31;         // 16B chunk within row
    const s16x8 v8 = *reinterpret_cast<const s16x8*>(vp + (size_t)c*NTOK + ck*8);
    *reinterpret_cast<s16x8*>(&vls[(size_t)c*VLP + ck*8]) = v8;
  }
  __syncthreads();

  s16x8 qf[4];
  #pragma unroll
  for (int qt = 0; qt < 4; ++qt)
    qf[qt] = *reinterpret_cast<const s16x8*>(qp + (wave*64 + qt*16 + u)*HC + g*8);

  f32x4 oacc[2][4];
  float m[4], l[4];
  #pragma unroll
  for (int qt = 0; qt < 4; ++qt) {
    m[qt] = -INFINITY; l[qt] = 0.f;
    #pragma unroll
    for (int ct = 0; ct < 2; ++ct) oacc[ct][qt] = (f32x4){0.f,0.f,0.f,0.f};
  }
  const float scale = 0.17677669529663687f;  // 1/sqrt(32)

  #pragma unroll 1
  for (int ch = 0; ch < 8; ++ch) {
    const int t0 = ch*32;
    const s16x8 kf0 = *reinterpret_cast<const s16x8*>(kp + (t0 + u)*HC + g*8);
    const s16x8 kf1 = *reinterpret_cast<const s16x8*>(kp + (t0 + 16 + u)*HC + g*8);
    s16x8 vf[2];
    #pragma unroll
    for (int ct = 0; ct < 2; ++ct) {
      const int c = ct*16 + u;
      const ushort4 lo = *reinterpret_cast<const ushort4*>(&vls[(size_t)c*VLP + t0 + g*4]);
      const ushort4 hi = *reinterpret_cast<const ushort4*>(&vls[(size_t)c*VLP + t0 + 16 + g*4]);
      s16x8 v;
      v[0]=(short)lo.x; v[1]=(short)lo.y; v[2]=(short)lo.z; v[3]=(short)lo.w;
      v[4]=(short)hi.x; v[5]=(short)hi.y; v[6]=(short)hi.z; v[7]=(short)hi.w;
      vf[ct] = v;
    }
    const f32x4 zero = {0.f,0.f,0.f,0.f};
    f32x4 s0[4], s1[4];
    #pragma unroll
    for (int qt = 0; qt < 4; ++qt) {
      s0[qt] = __builtin_amdgcn_mfma_f32_16x16x32_bf16(kf0, qf[qt], zero, 0, 0, 0);
      s1[qt] = __builtin_amdgcn_mfma_f32_16x16x32_bf16(kf1, qf[qt], zero, 0, 0, 0);
    }
    #pragma unroll
    for (int qt = 0; qt < 4; ++qt) {
      const int qh = wave*4 + qt;
      const float* r0 = &lrpe[(ch*2 + 0 - qh + 15)*31 + g*4 + 15 - u];
      const float* r1 = &lrpe[(ch*2 + 1 - qh + 15)*31 + g*4 + 15 - u];
      float p0[4], p1[4];
      #pragma unroll
      for (int r = 0; r < 4; ++r) {
        p0[r] = fmaf(s0[qt][r], scale, r0[r]);
        p1[r] = fmaf(s1[qt][r], scale, r1[r]);
      }
      float mt = fmaxf(fmaxf(fmaxf(p0[0],p0[1]), fmaxf(p0[2],p0[3])),
                       fmaxf(fmaxf(p1[0],p1[1]), fmaxf(p1[2],p1[3])));
      mt = fmaxf(mt, __shfl_xor(mt, 16));
      mt = fmaxf(mt, __shfl_xor(mt, 32));
      // defer-max (T13): only rescale when the tile max grows past m+8;
      // P then bounded by e^8, safe in bf16 with f32 accumulation.
      if (!__all(mt <= m[qt] + 8.0f)) {
        const float mnew = fmaxf(m[qt], mt);
        const float f = __expf(m[qt] - mnew);
        l[qt] *= f;
        #pragma unroll
        for (int ct = 0; ct < 2; ++ct)
          #pragma unroll
          for (int r = 0; r < 4; ++r) oacc[ct][qt][r] *= f;
        m[qt] = mnew;
      }
      float ls = 0.f;
      #pragma unroll
      for (int r = 0; r < 4; ++r) {
        p0[r] = __expf(p0[r] - m[qt]); ls += p0[r];
        p1[r] = __expf(p1[r] - m[qt]); ls += p1[r];
      }
      ls += __shfl_xor(ls, 16);
      ls += __shfl_xor(ls, 32);
      l[qt] += ls;
      union { s16x8 v; unsigned d[4]; } pf;
      pf.d[0] = cvtpk(p0[0], p0[1]);
      pf.d[1] = cvtpk(p0[2], p0[3]);
      pf.d[2] = cvtpk(p1[0], p1[1]);
      pf.d[3] = cvtpk(p1[2], p1[3]);
      oacc[0][qt] = __builtin_amdgcn_mfma_f32_16x16x32_bf16(vf[0], pf.v, oacc[0][qt], 0, 0, 0);
      oacc[1][qt] = __builtin_amdgcn_mfma_f32_16x16x32_bf16(vf[1], pf.v, oacc[1][qt], 0, 0, 0);
    }
  }

  const int b = win / NWIN_B, wl = win % NWIN_B;
  const int h0 = (wl / WDq) * 16;
  const int w = (wl % WDq) * 16 + u;
  #pragma unroll
  for (int qt = 0; qt < 4; ++qt) {
    const float inv = 1.f / l[qt];
    const int h = h0 + wave*4 + qt;
    const size_t row = (size_t)b*NPIX + (size_t)h*WIMG + w;
    #pragma unroll
    for (int ct = 0; ct < 2; ++ct) {
      const int c0 = head*HC + ct*16 + g*4;
      union { ushort4 v; unsigned d[2]; } vh;
      vh.d[0] = cvtpk(oacc[ct][qt][0]*inv, oacc[ct][qt][1]*inv);
      vh.d[1] = cvtpk(oacc[ct][qt][2]*inv, oacc[ct][qt][3]*inv);
      *reinterpret_cast<ushort4*>(athi + row*DIM + c0) = vh.v;
    }
  }
}

// ---------------------------------------------------------------------------
// K3: out = w_out @ attn + b_out, 2-term split MFMA, single-stage (R15),
// A from fragment-ordered W (ot 36..47).
// ---------------------------------------------------------------------------
__global__ __launch_bounds__(256, 3)
void k_proj_mfma(const u16* __restrict__ at, const u16* __restrict__ whiF,
                 const u16* __restrict__ wloF, const float* __restrict__ bout,
                 float* __restrict__ out) {
  const size_t P0 = (size_t)blockIdx.x * 64;
  const int tid = threadIdx.x;
  const int wave = tid >> 6, lane = tid & 63;
  const int u = lane & 15, g = lane >> 4;
  const int o_w = wave * 48;

  __shared__ u16 lb[3][4096];

  f32x4 acc[3][4];
  #pragma unroll
  for (int of = 0; of < 3; ++of)
    #pragma unroll
    for (int hf = 0; hf < 4; ++hf) acc[of][hf] = (f32x4){0.f,0.f,0.f,0.f};

  const int otb = 36 + wave*3;   // w_out fragment tiles
  #define AFO3(of, ks) ((size_t)(((otb + (of))*6 + (ks)) << 9) + (lane << 3))

  #pragma unroll
  for (int c = 0; c < 3; ++c)
    #pragma unroll
    for (int rep = 0; rep < 2; ++rep) {
      const int s = (rep*4 + wave)*64 + lane;
      const int row = s >> 3, chl = s & 7;
      gll16(at + (P0 + row)*DIM + c*64 + ((chl ^ (row & 7)) * 8),
            &lb[c][(size_t)((rep*4 + wave)*64) * 8]);
    }

  s16x8 Ah[3][3], Al[3][3];
  #pragma unroll
  for (int p = 0; p < 2; ++p)
    #pragma unroll
    for (int of = 0; of < 3; ++of) {
      Ah[p][of] = *reinterpret_cast<const s16x8*>(whiF + AFO3(of, p));
      Al[p][of] = *reinterpret_cast<const s16x8*>(wloF + AFO3(of, p));
    }

  asm volatile("s_waitcnt vmcnt(0)" ::: "memory");
  __builtin_amdgcn_s_barrier();

  #pragma unroll
  for (int ks = 0; ks < 6; ++ks) {
    if (ks < 4) {
      const int pn = (ks + 2) % 3;
      #pragma unroll
      for (int of = 0; of < 3; ++of) {
        Ah[pn][of] = *reinterpret_cast<const s16x8*>(whiF + AFO3(of, ks+2));
        Al[pn][of] = *reinterpret_cast<const s16x8*>(wloF + AFO3(of, ks+2));
      }
    }
    s16x8 bh[4];
    #pragma unroll
    for (int hf = 0; hf < 4; ++hf) {
      const int row = hf*16 + u;
      const int ch = ((ks & 1)*4 + g) ^ (row & 7);
      bh[hf] = *reinterpret_cast<const s16x8*>(&lb[ks >> 1][row*64 + ch*8]);
    }
    const int p = ks % 3;
    #pragma unroll
    for (int of = 0; of < 3; ++of)
      #pragma unroll
      for (int hf = 0; hf < 4; ++hf) {
        acc[of][hf] = __builtin_amdgcn_mfma_f32_16x16x32_bf16(Ah[p][of], bh[hf], acc[of][hf], 0, 0, 0);
        acc[of][hf] = __builtin_amdgcn_mfma_f32_16x16x32_bf16(Al[p][of], bh[hf], acc[of][hf], 0, 0, 0);
      }
  }
  #undef AFO3

  #pragma unroll
  for (int of = 0; of < 3; ++of) {
    const int ob = o_w + of*16 + g*4;
    const float4 bias = *reinterpret_cast<const float4*>(bout + ob);
    const float bb[4] = {bias.x, bias.y, bias.z, bias.w};
    #pragma unroll
    for (int hf = 0; hf < 4; ++hf) {
      const size_t pix = P0 + hf*16 + u;
      const int b = (int)(pix / NPIX);
      const int p = (int)(pix % NPIX);
      #pragma unroll
      for (int r = 0; r < 4; ++r)
        out[((size_t)(b*DIM + ob + r))*NPIX + p] = acc[of][hf][r] + bb[r];
    }
  }
}

extern "C" void kernel_launch(void* const* d_in, const int* in_sizes, int n_in,
                              void* d_out, int out_size, void* d_ws, size_t ws_size,
                              hipStream_t stream) {
  const float* x    = (const float*)d_in[0];
  const float* wqkv = (const float*)d_in[1];
  const float* bqkv = (const float*)d_in[2];
  const float* rpe  = (const float*)d_in[3];
  const float* wout = (const float*)d_in[4];
  const float* bout = (const float*)d_in[5];
  float* out = (float*)d_out;

  u16* xhi  = (u16*)d_ws;
  u16* whiF = xhi + XSP_E;
  u16* wloF = whiF + WSP_E;
  u16* qkv  = wloF + WSP_E;           // 3 * SLABSZ bf16
  u16* athi = qkv + 3*SLABSZ;
  // total: 5*XSP_E + 2*WSP_E u16 = 142 MB

  k_xsplit<<<dim3(NPIXT/64), 256, 0, stream>>>(x, xhi);
  k_wsplit<<<dim3(72), 256, 0, stream>>>(wqkv, wout, whiF, wloF);

  // 3456 blocks: slab-siblings of each pix tile share id%8 => same XCD
  k_qkv_mfma<<<dim3(3*NPIXT/64), 256, 0, stream>>>(xhi, whiF, wloF, bqkv, qkv);

  dim3 g2(NWIN, HEADS);
  k_attn<<<g2, 256, 0, stream>>>(qkv, rpe, athi);

  k_proj_mfma<<<dim3(NPIXT/64), 256, 0, stream>>>(athi, whiF, wloF, bout, out);
}

// Round 17
// 126.813 us; speedup vs baseline: 1.6632x; 1.1068x over previous
//
#include <hip/hip_runtime.h>
#include <math.h>

#define BATCH 2
#define DIM 192
#define HIMG 192
#define WIMG 192
#define NPIX (HIMG*WIMG)      // 36864
#define NPIXT ((size_t)BATCH*NPIX) // 73728 total pixel rows
#define HEADS 6
#define HC 32
#define NTOK 256
#define WDq 12
#define NWIN_B 144
#define NWIN (BATCH*NWIN_B)   // 288
#define RPE_N 961
#define SLABSZ ((size_t)NWIN*HEADS*NTOK*HC)   // 14,155,776 elems per q/k/v slab
#define XSP_E ((size_t)NPIXT*DIM)             // 14,155,776 u16 per split array
#define WSP_E ((size_t)(3*DIM+DIM)*DIM)       // 147,456 u16 (fragment-ordered)
#define VLP 264                                // k_attn V-stage row stride (u16)
#define L2E 1.4426950408889634f

typedef float f32x4 __attribute__((ext_vector_type(4)));
typedef short s16x8 __attribute__((ext_vector_type(8)));
typedef unsigned short u16;

__device__ __forceinline__ u16 f2bf(float f) {
  union { float f; unsigned u; } cv; cv.f = f;
  unsigned u = cv.u + 0x7fffu + ((cv.u >> 16) & 1u);   // RNE
  return (u16)(u >> 16);
}
__device__ __forceinline__ float bf2f(u16 h) {
  union { unsigned u; float f; } cv; cv.u = ((unsigned)h) << 16;
  return cv.f;
}
__device__ __forceinline__ void split2(float f, u16& hi, u16& lo) {
  hi = f2bf(f);
  lo = f2bf(f - bf2f(hi));
}
// packed f32x2 -> bf16x2 in ONE VALU op
__device__ __forceinline__ unsigned cvtpk(float a, float b) {
  unsigned r;
  asm("v_cvt_pk_bf16_f32 %0, %1, %2" : "=v"(r) : "v"(a), "v"(b));
  return r;
}
// raw exp2 (v_exp_f32 computes 2^x) — no log2e pre-multiply
__device__ __forceinline__ float ex2(float x) {
  float r;
  asm("v_exp_f32 %0, %1" : "=v"(r) : "v"(x));
  return r;
}
// async global->LDS, 16B per lane. LDS dest is wave-uniform base + lane*16.
__device__ __forceinline__ void gll16(const void* g, void* l) {
  __builtin_amdgcn_global_load_lds(
      (const __attribute__((address_space(1))) void*)g,
      (__attribute__((address_space(3))) void*)l, 16, 0, 0);
}

// ---------------------------------------------------------------------------
// T0: transpose x [b][c][pix] fp32 -> xT bf16 [b*pix][c] (float4 reads).
// ---------------------------------------------------------------------------
__global__ __launch_bounds__(256)
void k_xsplit(const float* __restrict__ x, u16* __restrict__ xhi) {
  const size_t P0 = (size_t)blockIdx.x * 64;
  const int b = (int)(P0 / NPIX);
  const int p0 = (int)(P0 % NPIX);
  __shared__ float lds[DIM][65];
  const int tid = threadIdx.x;
  const float* xb = x + (size_t)b*DIM*NPIX + p0;
  #pragma unroll
  for (int i = 0; i < 12; ++i) {
    const int idx = i*256 + tid;          // 0..3071
    const int c = idx >> 4;               // 0..191
    const int p4 = (idx & 15) << 2;       // 0..60
    const float4 v4 = *reinterpret_cast<const float4*>(xb + (size_t)c*NPIX + p4);
    lds[c][p4+0] = v4.x;
    lds[c][p4+1] = v4.y;
    lds[c][p4+2] = v4.z;
    lds[c][p4+3] = v4.w;
  }
  __syncthreads();
  const int wave = tid >> 6, lane = tid & 63;
  if (lane < 48) {
    const int c0 = lane * 4;
    #pragma unroll
    for (int rr = 0; rr < 16; ++rr) {
      const int p = wave*16 + rr;
      ushort4 vh;
      vh.x = f2bf(lds[c0+0][p]);
      vh.y = f2bf(lds[c0+1][p]);
      vh.z = f2bf(lds[c0+2][p]);
      vh.w = f2bf(lds[c0+3][p]);
      *reinterpret_cast<ushort4*>(xhi + (P0 + p)*DIM + c0) = vh;
    }
  }
}

// ---------------------------------------------------------------------------
// T1: split w_qkv/w_out into hi/lo u16 in MFMA-FRAGMENT order:
//   frag[(ot*6 + ks)*512 + lane*8 + i]  <->  w[row=ot*16+(lane&15)]
//                                             [k=ks*32+(lane>>4)*8+i]
// ot 0..35 = wqkv, 36..47 = wout.
// ---------------------------------------------------------------------------
__global__ __launch_bounds__(256)
void k_wsplit(const float* __restrict__ wqkv, const float* __restrict__ wout,
              u16* __restrict__ whi, u16* __restrict__ wlo) {
  const int gid = blockIdx.x*256 + threadIdx.x;      // 0..18431
  const int ot = gid / 384;
  const int rem = gid - ot*384;
  const int ks = rem >> 6;
  const int lane = rem & 63;
  const int u = lane & 15, g = lane >> 4;
  const int row = ot*16 + u;
  const float* src = (row < 3*DIM) ? (wqkv + (size_t)row*DIM + ks*32 + g*8)
                                   : (wout + (size_t)(row - 3*DIM)*DIM + ks*32 + g*8);
  const float4 a = *reinterpret_cast<const float4*>(src);
  const float4 b = *reinterpret_cast<const float4*>(src + 4);
  const float fv[8] = {a.x, a.y, a.z, a.w, b.x, b.y, b.z, b.w};
  s16x8 vh, vl;
  #pragma unroll
  for (int i = 0; i < 8; ++i) {
    u16 h, l;
    split2(fv[i], h, l);
    vh[i] = (short)h; vl[i] = (short)l;
  }
  *reinterpret_cast<s16x8*>(whi + (size_t)gid*8) = vh;
  *reinterpret_cast<s16x8*>(wlo + (size_t)gid*8) = vl;
}

// ---------------------------------------------------------------------------
// K1: qkv = w_qkv @ x + b_qkv, 2-term split MFMA (w hi/lo, x bf16).
// R15 structure (validated best): grid 3456, XCD-sibling swizzle, per-slab
// blocks, single-stage, rotating 2-ahead A prefetch, fragment-ordered A.
// R17: epilogue q/k packs via cvt_pk.
// ---------------------------------------------------------------------------
__global__ __launch_bounds__(256, 3)
void k_qkv_mfma(const u16* __restrict__ xhi,
                const u16* __restrict__ whiF, const u16* __restrict__ wloF,
                const float* __restrict__ bqkv, u16* __restrict__ qkv) {
  const int id = blockIdx.x;                 // 0..3455
  const int slot = id & 7;
  const int grp = id >> 3;                   // 0..431
  const int slab = grp % 3;
  const size_t P0 = (size_t)(slot + 8*(grp/3)) * 64;
  const int tid = threadIdx.x;
  const int wave = tid >> 6, lane = tid & 63;
  const int u = lane & 15, g = lane >> 4;
  const int o_w = wave * 48;                 // 4 waves cover 192 o

  // [chunk][64 rows x 64 k-elems] bf16, 8KB per plane, 24KB total
  __shared__ u16 lb[3][4096];

  f32x4 acc[3][4];
  #pragma unroll
  for (int of = 0; of < 3; ++of)
    #pragma unroll
    for (int hf = 0; hf < 4; ++hf) acc[of][hf] = (f32x4){0.f,0.f,0.f,0.f};

  // fragment-ordered A base for this wave's 3 row-tiles
  const int otb = slab*12 + wave*3;
  #define AFO(of, ks) ((size_t)(((otb + (of))*6 + (ks)) << 9) + (lane << 3))

  // stage ALL 3 chunks (global source pre-swizzled, LDS dest linear; read
  // applies the same XOR involution -> conflict-free ds_read_b128)
  #pragma unroll
  for (int c = 0; c < 3; ++c)
    #pragma unroll
    for (int rep = 0; rep < 2; ++rep) {
      const int s = (rep*4 + wave)*64 + lane;
      const int row = s >> 3, chl = s & 7;
      gll16(xhi + (P0 + row)*DIM + c*64 + ((chl ^ (row & 7)) * 8),
            &lb[c][(size_t)((rep*4 + wave)*64) * 8]);
    }

  // A prefetch: 3 rotating sets, 2-ahead
  s16x8 Ah[3][3], Al[3][3];
  #pragma unroll
  for (int p = 0; p < 2; ++p)
    #pragma unroll
    for (int of = 0; of < 3; ++of) {
      Ah[p][of] = *reinterpret_cast<const s16x8*>(whiF + AFO(of, p));
      Al[p][of] = *reinterpret_cast<const s16x8*>(wloF + AFO(of, p));
    }

  asm volatile("s_waitcnt vmcnt(0)" ::: "memory");   // stage + A0/A1 done
  __builtin_amdgcn_s_barrier();                      // the only barrier

  #pragma unroll
  for (int ks = 0; ks < 6; ++ks) {
    if (ks < 4) {
      const int pn = (ks + 2) % 3;                   // compile-time after unroll
      #pragma unroll
      for (int of = 0; of < 3; ++of) {
        Ah[pn][of] = *reinterpret_cast<const s16x8*>(whiF + AFO(of, ks+2));
        Al[pn][of] = *reinterpret_cast<const s16x8*>(wloF + AFO(of, ks+2));
      }
    }
    s16x8 bh[4];
    #pragma unroll
    for (int hf = 0; hf < 4; ++hf) {
      const int row = hf*16 + u;
      const int ch = ((ks & 1)*4 + g) ^ (row & 7);
      bh[hf] = *reinterpret_cast<const s16x8*>(&lb[ks >> 1][row*64 + ch*8]);
    }
    const int p = ks % 3;
    #pragma unroll
    for (int of = 0; of < 3; ++of)
      #pragma unroll
      for (int hf = 0; hf < 4; ++hf) {
        acc[of][hf] = __builtin_amdgcn_mfma_f32_16x16x32_bf16(Ah[p][of], bh[hf], acc[of][hf], 0, 0, 0);
        acc[of][hf] = __builtin_amdgcn_mfma_f32_16x16x32_bf16(Al[p][of], bh[hf], acc[of][hf], 0, 0, 0);
      }
  }
  #undef AFO

  // epilogue: windowed scatter, bf16 (q/k packed via cvt_pk)
  u16* base = qkv + (size_t)slab * SLABSZ;
  const float* bq = bqkv + slab*DIM;
  #pragma unroll
  for (int of = 0; of < 3; ++of) {
    const int ob = o_w + of*16 + g*4;        // 4 consecutive o (+r)
    const int hd = ob >> 5, cc = ob & 31;
    const float4 bias = *reinterpret_cast<const float4*>(bq + ob);
    #pragma unroll
    for (int hf = 0; hf < 4; ++hf) {
      const size_t pix = P0 + hf*16 + u;
      const int b = (int)(pix / NPIX);
      const int p = (int)(pix % NPIX);
      const int h = p / WIMG, w = p % WIMG;
      const int win = b*NWIN_B + (h >> 4)*WDq + (w >> 4);
      const int t = (h & 15)*16 + (w & 15);
      const float v0 = acc[of][hf][0] + bias.x;
      const float v1 = acc[of][hf][1] + bias.y;
      const float v2 = acc[of][hf][2] + bias.z;
      const float v3 = acc[of][hf][3] + bias.w;
      if (slab == 2) {
        u16* p2 = base + (((size_t)(win*HEADS + hd))*HC + cc)*NTOK + t;
        p2[0*NTOK] = f2bf(v0);
        p2[1*NTOK] = f2bf(v1);
        p2[2*NTOK] = f2bf(v2);
        p2[3*NTOK] = f2bf(v3);
      } else {
        union { ushort4 v; unsigned d[2]; } st;
        st.d[0] = cvtpk(v0, v1);
        st.d[1] = cvtpk(v2, v3);
        *reinterpret_cast<ushort4*>(base + (((size_t)(win*HEADS + hd))*NTOK + t)*HC + cc) = st.v;
      }
    }
  }
}

// ---------------------------------------------------------------------------
// K2: MFMA flash attention. R17: log2-domain softmax (rpe and scale folded
// by log2e at load; exp2 via raw v_exp_f32 -> one op per exp) and
// __launch_bounds__(256,4) to lift the 2-blocks/CU occupancy cap.
// ---------------------------------------------------------------------------
__global__ __launch_bounds__(256, 4)
void k_attn(const u16* __restrict__ qkv, const float* __restrict__ rpe,
            u16* __restrict__ athi) {
  const int win = blockIdx.x;
  const int head = blockIdx.y;
  const int tid = threadIdx.x;
  const int wave = tid >> 6;
  const int lane = tid & 63;
  const int u = lane & 15;
  const int g = lane >> 4;

  __shared__ float lrpe[RPE_N];
  __shared__ u16 vls[32*VLP];    // V [c][t+pad], 16.5KB

  const size_t wh = (size_t)(win*HEADS + head);
  const u16* qp = qkv + wh*NTOK*HC;
  const u16* kp = qkv + SLABSZ + wh*NTOK*HC;
  const u16* vp = qkv + 2*SLABSZ + wh*HC*NTOK;

  // rpe pre-scaled by log2e: softmax runs in the log2 domain
  for (int i = tid; i < RPE_N; i += 256) lrpe[i] = rpe[head*RPE_N + i] * L2E;
  #pragma unroll
  for (int i = 0; i < 4; ++i) {
    const int flat = i*256 + tid;     // 0..1023
    const int c = flat >> 5;          // 0..31
    const int ck = flat & 31;         // 16B chunk within row
    const s16x8 v8 = *reinterpret_cast<const s16x8*>(vp + (size_t)c*NTOK + ck*8);
    *reinterpret_cast<s16x8*>(&vls[(size_t)c*VLP + ck*8]) = v8;
  }
  __syncthreads();

  s16x8 qf[4];
  #pragma unroll
  for (int qt = 0; qt < 4; ++qt)
    qf[qt] = *reinterpret_cast<const s16x8*>(qp + (wave*64 + qt*16 + u)*HC + g*8);

  f32x4 oacc[2][4];
  float m[4], l[4];
  #pragma unroll
  for (int qt = 0; qt < 4; ++qt) {
    m[qt] = -INFINITY; l[qt] = 0.f;
    #pragma unroll
    for (int ct = 0; ct < 2; ++ct) oacc[ct][qt] = (f32x4){0.f,0.f,0.f,0.f};
  }
  const float scl2 = 0.17677669529663687f * L2E;   // 1/sqrt(32) * log2e

  #pragma unroll 1
  for (int ch = 0; ch < 8; ++ch) {
    const int t0 = ch*32;
    const s16x8 kf0 = *reinterpret_cast<const s16x8*>(kp + (t0 + u)*HC + g*8);
    const s16x8 kf1 = *reinterpret_cast<const s16x8*>(kp + (t0 + 16 + u)*HC + g*8);
    s16x8 vf[2];
    #pragma unroll
    for (int ct = 0; ct < 2; ++ct) {
      const int c = ct*16 + u;
      const ushort4 lo = *reinterpret_cast<const ushort4*>(&vls[(size_t)c*VLP + t0 + g*4]);
      const ushort4 hi = *reinterpret_cast<const ushort4*>(&vls[(size_t)c*VLP + t0 + 16 + g*4]);
      s16x8 v;
      v[0]=(short)lo.x; v[1]=(short)lo.y; v[2]=(short)lo.z; v[3]=(short)lo.w;
      v[4]=(short)hi.x; v[5]=(short)hi.y; v[6]=(short)hi.z; v[7]=(short)hi.w;
      vf[ct] = v;
    }
    const f32x4 zero = {0.f,0.f,0.f,0.f};
    f32x4 s0[4], s1[4];
    #pragma unroll
    for (int qt = 0; qt < 4; ++qt) {
      s0[qt] = __builtin_amdgcn_mfma_f32_16x16x32_bf16(kf0, qf[qt], zero, 0, 0, 0);
      s1[qt] = __builtin_amdgcn_mfma_f32_16x16x32_bf16(kf1, qf[qt], zero, 0, 0, 0);
    }
    #pragma unroll
    for (int qt = 0; qt < 4; ++qt) {
      const int qh = wave*4 + qt;
      const float* r0 = &lrpe[(ch*2 + 0 - qh + 15)*31 + g*4 + 15 - u];
      const float* r1 = &lrpe[(ch*2 + 1 - qh + 15)*31 + g*4 + 15 - u];
      float p0[4], p1[4];
      #pragma unroll
      for (int r = 0; r < 4; ++r) {
        p0[r] = fmaf(s0[qt][r], scl2, r0[r]);   // log2-domain scores
        p1[r] = fmaf(s1[qt][r], scl2, r1[r]);
      }
      float mt = fmaxf(fmaxf(fmaxf(p0[0],p0[1]), fmaxf(p0[2],p0[3])),
                       fmaxf(fmaxf(p1[0],p1[1]), fmaxf(p1[2],p1[3])));
      mt = fmaxf(mt, __shfl_xor(mt, 16));
      mt = fmaxf(mt, __shfl_xor(mt, 32));
      // defer-max (T13): threshold 8 nats = 11.542 log2-units
      if (!__all(mt <= m[qt] + 11.5416f)) {
        const float mnew = fmaxf(m[qt], mt);
        const float f = ex2(m[qt] - mnew);
        l[qt] *= f;
        #pragma unroll
        for (int ct = 0; ct < 2; ++ct)
          #pragma unroll
          for (int r = 0; r < 4; ++r) oacc[ct][qt][r] *= f;
        m[qt] = mnew;
      }
      float ls = 0.f;
      #pragma unroll
      for (int r = 0; r < 4; ++r) {
        p0[r] = ex2(p0[r] - m[qt]); ls += p0[r];
        p1[r] = ex2(p1[r] - m[qt]); ls += p1[r];
      }
      ls += __shfl_xor(ls, 16);
      ls += __shfl_xor(ls, 32);
      l[qt] += ls;
      union { s16x8 v; unsigned d[4]; } pf;
      pf.d[0] = cvtpk(p0[0], p0[1]);
      pf.d[1] = cvtpk(p0[2], p0[3]);
      pf.d[2] = cvtpk(p1[0], p1[1]);
      pf.d[3] = cvtpk(p1[2], p1[3]);
      oacc[0][qt] = __builtin_amdgcn_mfma_f32_16x16x32_bf16(vf[0], pf.v, oacc[0][qt], 0, 0, 0);
      oacc[1][qt] = __builtin_amdgcn_mfma_f32_16x16x32_bf16(vf[1], pf.v, oacc[1][qt], 0, 0, 0);
    }
  }

  const int b = win / NWIN_B, wl = win % NWIN_B;
  const int h0 = (wl / WDq) * 16;
  const int w = (wl % WDq) * 16 + u;
  #pragma unroll
  for (int qt = 0; qt < 4; ++qt) {
    const float inv = 1.f / l[qt];
    const int h = h0 + wave*4 + qt;
    const size_t row = (size_t)b*NPIX + (size_t)h*WIMG + w;
    #pragma unroll
    for (int ct = 0; ct < 2; ++ct) {
      const int c0 = head*HC + ct*16 + g*4;
      union { ushort4 v; unsigned d[2]; } vh;
      vh.d[0] = cvtpk(oacc[ct][qt][0]*inv, oacc[ct][qt][1]*inv);
      vh.d[1] = cvtpk(oacc[ct][qt][2]*inv, oacc[ct][qt][3]*inv);
      *reinterpret_cast<ushort4*>(athi + row*DIM + c0) = vh.v;
    }
  }
}

// ---------------------------------------------------------------------------
// K3: out = w_out @ attn + b_out, 2-term split MFMA, single-stage (R15),
// A from fragment-ordered W (ot 36..47).
// ---------------------------------------------------------------------------
__global__ __launch_bounds__(256, 3)
void k_proj_mfma(const u16* __restrict__ at, const u16* __restrict__ whiF,
                 const u16* __restrict__ wloF, const float* __restrict__ bout,
                 float* __restrict__ out) {
  const size_t P0 = (size_t)blockIdx.x * 64;
  const int tid = threadIdx.x;
  const int wave = tid >> 6, lane = tid & 63;
  const int u = lane & 15, g = lane >> 4;
  const int o_w = wave * 48;

  __shared__ u16 lb[3][4096];

  f32x4 acc[3][4];
  #pragma unroll
  for (int of = 0; of < 3; ++of)
    #pragma unroll
    for (int hf = 0; hf < 4; ++hf) acc[of][hf] = (f32x4){0.f,0.f,0.f,0.f};

  const int otb = 36 + wave*3;   // w_out fragment tiles
  #define AFO3(of, ks) ((size_t)(((otb + (of))*6 + (ks)) << 9) + (lane << 3))

  #pragma unroll
  for (int c = 0; c < 3; ++c)
    #pragma unroll
    for (int rep = 0; rep < 2; ++rep) {
      const int s = (rep*4 + wave)*64 + lane;
      const int row = s >> 3, chl = s & 7;
      gll16(at + (P0 + row)*DIM + c*64 + ((chl ^ (row & 7)) * 8),
            &lb[c][(size_t)((rep*4 + wave)*64) * 8]);
    }

  s16x8 Ah[3][3], Al[3][3];
  #pragma unroll
  for (int p = 0; p < 2; ++p)
    #pragma unroll
    for (int of = 0; of < 3; ++of) {
      Ah[p][of] = *reinterpret_cast<const s16x8*>(whiF + AFO3(of, p));
      Al[p][of] = *reinterpret_cast<const s16x8*>(wloF + AFO3(of, p));
    }

  asm volatile("s_waitcnt vmcnt(0)" ::: "memory");
  __builtin_amdgcn_s_barrier();

  #pragma unroll
  for (int ks = 0; ks < 6; ++ks) {
    if (ks < 4) {
      const int pn = (ks + 2) % 3;
      #pragma unroll
      for (int of = 0; of < 3; ++of) {
        Ah[pn][of] = *reinterpret_cast<const s16x8*>(whiF + AFO3(of, ks+2));
        Al[pn][of] = *reinterpret_cast<const s16x8*>(wloF + AFO3(of, ks+2));
      }
    }
    s16x8 bh[4];
    #pragma unroll
    for (int hf = 0; hf < 4; ++hf) {
      const int row = hf*16 + u;
      const int ch = ((ks & 1)*4 + g) ^ (row & 7);
      bh[hf] = *reinterpret_cast<const s16x8*>(&lb[ks >> 1][row*64 + ch*8]);
    }
    const int p = ks % 3;
    #pragma unroll
    for (int of = 0; of < 3; ++of)
      #pragma unroll
      for (int hf = 0; hf < 4; ++hf) {
        acc[of][hf] = __builtin_amdgcn_mfma_f32_16x16x32_bf16(Ah[p][of], bh[hf], acc[of][hf], 0, 0, 0);
        acc[of][hf] = __builtin_amdgcn_mfma_f32_16x16x32_bf16(Al[p][of], bh[hf], acc[of][hf], 0, 0, 0);
      }
  }
  #undef AFO3

  #pragma unroll
  for (int of = 0; of < 3; ++of) {
    const int ob = o_w + of*16 + g*4;
    const float4 bias = *reinterpret_cast<const float4*>(bout + ob);
    const float bb[4] = {bias.x, bias.y, bias.z, bias.w};
    #pragma unroll
    for (int hf = 0; hf < 4; ++hf) {
      const size_t pix = P0 + hf*16 + u;
      const int b = (int)(pix / NPIX);
      const int p = (int)(pix % NPIX);
      #pragma unroll
      for (int r = 0; r < 4; ++r)
        out[((size_t)(b*DIM + ob + r))*NPIX + p] = acc[of][hf][r] + bb[r];
    }
  }
}

extern "C" void kernel_launch(void* const* d_in, const int* in_sizes, int n_in,
                              void* d_out, int out_size, void* d_ws, size_t ws_size,
                              hipStream_t stream) {
  const float* x    = (const float*)d_in[0];
  const float* wqkv = (const float*)d_in[1];
  const float* bqkv = (const float*)d_in[2];
  const float* rpe  = (const float*)d_in[3];
  const float* wout = (const float*)d_in[4];
  const float* bout = (const float*)d_in[5];
  float* out = (float*)d_out;

  u16* xhi  = (u16*)d_ws;
  u16* whiF = xhi + XSP_E;
  u16* wloF = whiF + WSP_E;
  u16* qkv  = wloF + WSP_E;           // 3 * SLABSZ bf16
  u16* athi = qkv + 3*SLABSZ;
  // total: 5*XSP_E + 2*WSP_E u16 = 142 MB

  k_xsplit<<<dim3(NPIXT/64), 256, 0, stream>>>(x, xhi);
  k_wsplit<<<dim3(72), 256, 0, stream>>>(wqkv, wout, whiF, wloF);

  // 3456 blocks: slab-siblings of each pix tile share id%8 => same XCD
  k_qkv_mfma<<<dim3(3*NPIXT/64), 256, 0, stream>>>(xhi, whiF, wloF, bqkv, qkv);

  dim3 g2(NWIN, HEADS);
  k_attn<<<g2, 256, 0, stream>>>(qkv, rpe, athi);

  k_proj_mfma<<<dim3(NPIXT/64), 256, 0, stream>>>(athi, whiF, wloF, bout, out);
}